// Round 4
// baseline (251.286 us; speedup 1.0000x reference)
//
#include <hip/hip_runtime.h>

typedef float v2f __attribute__((ext_vector_type(2)));

#define IN_F 4096
#define OUT_F 11008
#define GROUPSIZE 128
#define NGROUPS 32
#define QROWS 512
#define ZCOLS 1376

#define TILE_N 128
#define NTILES 86                 // OUT_F / TILE_N
#define KSPL 32                   // one group per K-split block
#define PART_STRIDE 512           // floats per (tile, ks) partial: 4 m * 128 c
#define PART_OFF_BYTES 4096
#define WS_FUSED_BYTES (PART_OFF_BYTES + (size_t)NTILES * KSPL * PART_STRIDE * sizeof(float))
#define WS_OLD_BYTES ((size_t)8 * 4 * OUT_F * sizeof(float))

// ================= Fused split-K kernel with last-block reduction ===========
// Grid (NTILES, KSPL), block 256 = 4 waves. Block (bx, g): group g, cols
// [bx*128, bx*128+128). Wave kq does rows g*16+kq*4 .. +3. Lane owns 2 cols.
__global__ __launch_bounds__(256) void gptq_fused_splitk(
    const float* __restrict__ x,       // [4, IN_F]
    const float* __restrict__ scales,  // [NGROUPS, OUT_F]
    const float* __restrict__ bias,    // [OUT_F]
    const int*   __restrict__ qweight, // [QROWS, OUT_F]
    const int*   __restrict__ qzeros,  // [NGROUPS, ZCOLS]
    float*       __restrict__ out,     // [4, OUT_F]
    int*         __restrict__ cnt,     // [NTILES], zeroed each launch
    float*       __restrict__ part)    // [NTILES][KSPL][512]
{
    __shared__ float red[4][4][TILE_N];  // [kq][m][c] = 8 KB
    __shared__ int lastFlag;

    const int tid  = threadIdx.x;
    const int lane = tid & 63;
    const int kq   = __builtin_amdgcn_readfirstlane(tid >> 6);  // uniform
    const int bx   = blockIdx.x;
    const int g    = blockIdx.y;
    const int c0   = bx * TILE_N + lane * 2;

    // zeros + scales for the 2 columns
    const unsigned qz = (unsigned)qzeros[g * ZCOLS + (c0 >> 3)];
    const unsigned sh = 4u * (unsigned)(c0 & 7);
    const float z0 = (float)(((qz >> sh) & 0xFu) + 1u);
    const float z1 = (float)(((qz >> (sh + 4u)) & 0xFu) + 1u);
    const v2f sc = *(const v2f*)(scales + g * OUT_F + c0);

    const int r0 = g * 16 + kq * 4;

    // 4 x dwordx2 loads issued upfront (8 packed int32s = 2 cols x 32 K)
    const int2 w0 = *(const int2*)(qweight + (r0 + 0) * OUT_F + c0);
    const int2 w1 = *(const int2*)(qweight + (r0 + 1) * OUT_F + c0);
    const int2 w2 = *(const int2*)(qweight + (r0 + 2) * OUT_F + c0);
    const int2 w3 = *(const int2*)(qweight + (r0 + 3) * OUT_F + c0);
    const int2 ww[4] = {w0, w1, w2, w3};

    float acc0[4] = {0.f, 0.f, 0.f, 0.f};   // [m], col 0
    float acc1[4] = {0.f, 0.f, 0.f, 0.f};   // [m], col 1

    #pragma unroll
    for (int t = 0; t < 4; ++t) {
        const unsigned wa = (unsigned)ww[t].x;
        const unsigned wb = (unsigned)ww[t].y;
        const unsigned la = wa & 0x0F0F0F0Fu, ha = (wa >> 4) & 0x0F0F0F0Fu;
        const unsigned lb = wb & 0x0F0F0F0Fu, hb = (wb >> 4) & 0x0F0F0F0Fu;
        float qa[8], qb[8];
        qa[0] = (float)(la & 0xFFu);         qa[1] = (float)(ha & 0xFFu);
        qa[2] = (float)((la >> 8) & 0xFFu);  qa[3] = (float)((ha >> 8) & 0xFFu);
        qa[4] = (float)((la >> 16) & 0xFFu); qa[5] = (float)((ha >> 16) & 0xFFu);
        qa[6] = (float)(la >> 24);           qa[7] = (float)(ha >> 24);
        qb[0] = (float)(lb & 0xFFu);         qb[1] = (float)(hb & 0xFFu);
        qb[2] = (float)((lb >> 8) & 0xFFu);  qb[3] = (float)((hb >> 8) & 0xFFu);
        qb[4] = (float)((lb >> 16) & 0xFFu); qb[5] = (float)((hb >> 16) & 0xFFu);
        qb[6] = (float)(lb >> 24);           qb[7] = (float)(hb >> 24);

        const int k0 = (r0 + t) * 8;         // wave-uniform
        #pragma unroll
        for (int j = 0; j < 8; ++j) {
            const float d0 = qa[j] - z0;
            const float d1 = qb[j] - z1;
            #pragma unroll
            for (int m = 0; m < 4; ++m) {
                const float xf = x[m * IN_F + k0 + j];   // uniform -> s_load
                acc0[m] += xf * d0;
                acc1[m] += xf * d1;
            }
        }
    }

    // in-block reduction over the 4 waves (kq), scale applied here
    #pragma unroll
    for (int m = 0; m < 4; ++m) {
        v2f r;
        r.x = acc0[m] * sc.x;
        r.y = acc1[m] * sc.y;
        *(v2f*)&red[kq][m][lane * 2] = r;
    }
    __syncthreads();

    v2f p; p.x = 0.f; p.y = 0.f;
    const float* rbase = &red[0][0][0];
    #pragma unroll
    for (int k = 0; k < 4; ++k) {
        const v2f q = *(const v2f*)(rbase + k * PART_STRIDE + 2 * tid);
        p.x += q.x;
        p.y += q.y;
    }
    *(v2f*)(part + ((size_t)bx * KSPL + g) * PART_STRIDE + 2 * tid) = p;

    // release: partial visible device-wide, then signal arrival
    __threadfence();
    __syncthreads();
    if (tid == 0)
        lastFlag = (atomicAdd(&cnt[bx], 1) == KSPL - 1);
    __syncthreads();
    if (!lastFlag) return;

    // last block of this tile: acquire, then reduce all 32 partials (fixed order)
    __threadfence();
    const int o = 2 * tid;                   // 512 outputs, 2 per thread
    float s0 = 0.f, s1 = 0.f;
    const float* pb = part + (size_t)bx * KSPL * PART_STRIDE + o;
    #pragma unroll 8
    for (int ks = 0; ks < KSPL; ++ks) {
        const v2f q = *(const v2f*)(pb + (size_t)ks * PART_STRIDE);
        s0 += q.x;
        s1 += q.y;
    }
    const int m = o >> 7;
    const int c = o & 127;
    const int n = bx * TILE_N + c;
    out[m * OUT_F + n]     = s0 + bias[n];
    out[m * OUT_F + n + 1] = s1 + bias[n + 1];
}

// ================= Fallback: round-2 proven two-stage =======================
__global__ __launch_bounds__(256) void gptq_partial_kernel(
    const float* __restrict__ x, const float* __restrict__ scales,
    const int* __restrict__ qweight, const int* __restrict__ qzeros,
    float* __restrict__ ws)
{
    __shared__ float part[4][4][64];
    const int tid = threadIdx.x;
    const int col = tid & 63;
    const int kp  = tid >> 6;
    const int n   = blockIdx.x * 64 + col;
    const int g   = blockIdx.y * 4 + kp;
    const int gu  = __builtin_amdgcn_readfirstlane(g);
    const unsigned qz = (unsigned)qzeros[g * ZCOLS + (n >> 3)];
    const float zf = (float)(((qz >> (4u * (unsigned)(n & 7))) & 0xFu) + 1u);
    const float sc = scales[g * OUT_F + n];
    float ga[4] = {0.f, 0.f, 0.f, 0.f};
    const int kkbase = gu * (GROUPSIZE / 8);
    #pragma unroll
    for (int t = 0; t < GROUPSIZE / 8; ++t) {
        const int kk = kkbase + t;
        const unsigned w = (unsigned)qweight[kk * OUT_F + n];
        const unsigned lo = w & 0x0F0F0F0Fu;
        const unsigned hi = (w >> 4) & 0x0F0F0F0Fu;
        float q[8];
        q[0] = (float)(lo & 0xFFu);         q[1] = (float)(hi & 0xFFu);
        q[2] = (float)((lo >> 8) & 0xFFu);  q[3] = (float)((hi >> 8) & 0xFFu);
        q[4] = (float)((lo >> 16) & 0xFFu); q[5] = (float)((hi >> 16) & 0xFFu);
        q[6] = (float)(lo >> 24);           q[7] = (float)(hi >> 24);
        const int k0 = kk * 8;
        #pragma unroll
        for (int j = 0; j < 8; ++j) {
            const float d = q[j] - zf;
            #pragma unroll
            for (int m = 0; m < 4; ++m) ga[m] += x[m * IN_F + k0 + j] * d;
        }
    }
    #pragma unroll
    for (int m = 0; m < 4; ++m) part[kp][m][col] = sc * ga[m];
    __syncthreads();
    const int m = tid >> 6;
    const int c = tid & 63;
    const int nn = blockIdx.x * 64 + c;
    const float s = part[0][m][c] + part[1][m][c] + part[2][m][c] + part[3][m][c];
    ws[(blockIdx.y * 4 + m) * OUT_F + nn] = s;
}

__global__ __launch_bounds__(256) void gptq_reduce_kernel(
    const float* __restrict__ ws, const float* __restrict__ bias,
    float* __restrict__ out)
{
    const int n = blockIdx.x * 256 + threadIdx.x;
    const int m = blockIdx.y;
    float s = bias[n];
    #pragma unroll
    for (int ks = 0; ks < 8; ++ks) s += ws[(ks * 4 + m) * OUT_F + n];
    out[m * OUT_F + n] = s;
}

extern "C" void kernel_launch(void* const* d_in, const int* in_sizes, int n_in,
                              void* d_out, int out_size, void* d_ws, size_t ws_size,
                              hipStream_t stream) {
    const float* x       = (const float*)d_in[0];
    const float* scales  = (const float*)d_in[1];
    const float* bias    = (const float*)d_in[2];
    const int*   qweight = (const int*)d_in[3];
    const int*   qzeros  = (const int*)d_in[4];
    float*       out     = (float*)d_out;

    if (ws_size >= WS_FUSED_BYTES) {
        int*   cnt  = (int*)d_ws;
        float* part = (float*)((char*)d_ws + PART_OFF_BYTES);
        hipMemsetAsync(cnt, 0, NTILES * sizeof(int), stream);
        dim3 grid(NTILES, KSPL);   // (86, 32) = 2752 blocks
        gptq_fused_splitk<<<grid, 256, 0, stream>>>(
            x, scales, bias, qweight, qzeros, out, cnt, part);
    } else if (ws_size >= WS_OLD_BYTES) {
        float* ws = (float*)d_ws;
        dim3 g1(OUT_F / 64, 8);
        gptq_partial_kernel<<<g1, 256, 0, stream>>>(x, scales, qweight, qzeros, ws);
        dim3 g2(OUT_F / 256, 4);
        gptq_reduce_kernel<<<g2, 256, 0, stream>>>(ws, bias, out);
    }
}

// Round 5
// 17.530 us; speedup vs baseline: 14.3344x; 14.3344x over previous
//
#include <hip/hip_runtime.h>

typedef float v2f __attribute__((ext_vector_type(2)));

#define IN_F 4096
#define OUT_F 11008
#define GROUPSIZE 128
#define NGROUPS 32
#define QROWS 512
#define ZCOLS 1376

#define TILE_N 128
#define NTILES 86                 // OUT_F / TILE_N
#define WS_NEW_BYTES ((size_t)NGROUPS * 4 * OUT_F * sizeof(float))   // 5.6 MB
#define WS_OLD_BYTES ((size_t)8 * 4 * OUT_F * sizeof(float))         // 1.4 MB

// ============ Stage 1: grid (NTILES, NGROUPS), block 256 = 4 waves ==========
// Block (bx, g): cols [bx*128, +128), group g (16 packed rows, 128 K).
// Wave kq handles 4 packed rows; lane owns 2 adjacent columns (int2 loads).
__global__ __launch_bounds__(256) void gptq_s1(
    const float* __restrict__ x,       // [4, IN_F]
    const float* __restrict__ scales,  // [NGROUPS, OUT_F]
    const int*   __restrict__ qweight, // [QROWS, OUT_F]
    const int*   __restrict__ qzeros,  // [NGROUPS, ZCOLS]
    float*       __restrict__ ws)      // [NGROUPS, 4, OUT_F]
{
    __shared__ float red[4][4][TILE_N];   // [kq][m][c] = 8 KB

    const int tid  = threadIdx.x;
    const int lane = tid & 63;
    const int kq   = __builtin_amdgcn_readfirstlane(tid >> 6);   // 0..3 uniform
    const int bx   = blockIdx.x;
    const int g    = blockIdx.y;
    const int c0   = bx * TILE_N + lane * 2;

    // zeros + scales for the two columns (both nibbles are in one qzeros dword)
    const unsigned qz = (unsigned)qzeros[g * ZCOLS + (c0 >> 3)];
    const unsigned sh = 4u * (unsigned)(c0 & 7);
    const float z0 = (float)(((qz >> sh) & 0xFu) + 1u);
    const float z1 = (float)(((qz >> (sh + 4u)) & 0xFu) + 1u);
    const v2f sc = *(const v2f*)(scales + g * OUT_F + c0);

    const int r0 = g * 16 + kq * 4;       // this wave's 4 packed rows

    // issue all weight loads upfront (4 x dwordx2, fully coalesced)
    const int2 w0 = *(const int2*)(qweight + (r0 + 0) * OUT_F + c0);
    const int2 w1 = *(const int2*)(qweight + (r0 + 1) * OUT_F + c0);
    const int2 w2 = *(const int2*)(qweight + (r0 + 2) * OUT_F + c0);
    const int2 w3 = *(const int2*)(qweight + (r0 + 3) * OUT_F + c0);
    const int2 ww[4] = {w0, w1, w2, w3};

    float acc0[4] = {0.f, 0.f, 0.f, 0.f};    // [m], col c0
    float acc1[4] = {0.f, 0.f, 0.f, 0.f};    // [m], col c0+1

    #pragma unroll
    for (int t = 0; t < 4; ++t) {
        const unsigned wa = (unsigned)ww[t].x;
        const unsigned wb = (unsigned)ww[t].y;
        const unsigned la = wa & 0x0F0F0F0Fu, ha = (wa >> 4) & 0x0F0F0F0Fu;
        const unsigned lb = wb & 0x0F0F0F0Fu, hb = (wb >> 4) & 0x0F0F0F0Fu;
        float qa[8], qb[8];
        qa[0] = (float)(la & 0xFFu);         qa[1] = (float)(ha & 0xFFu);
        qa[2] = (float)((la >> 8) & 0xFFu);  qa[3] = (float)((ha >> 8) & 0xFFu);
        qa[4] = (float)((la >> 16) & 0xFFu); qa[5] = (float)((ha >> 16) & 0xFFu);
        qa[6] = (float)(la >> 24);           qa[7] = (float)(ha >> 24);
        qb[0] = (float)(lb & 0xFFu);         qb[1] = (float)(hb & 0xFFu);
        qb[2] = (float)((lb >> 8) & 0xFFu);  qb[3] = (float)((hb >> 8) & 0xFFu);
        qb[4] = (float)((lb >> 16) & 0xFFu); qb[5] = (float)((hb >> 16) & 0xFFu);
        qb[6] = (float)(lb >> 24);           qb[7] = (float)(hb >> 24);

        const int k0 = (r0 + t) * 8;          // wave-uniform -> scalar x loads
        #pragma unroll
        for (int j = 0; j < 8; ++j) {
            const float d0 = qa[j] - z0;
            const float d1 = qb[j] - z1;
            #pragma unroll
            for (int m = 0; m < 4; ++m) {
                const float xf = x[m * IN_F + k0 + j];
                acc0[m] += xf * d0;
                acc1[m] += xf * d1;
            }
        }
    }

    // in-block reduction over the 4 waves; scale applied once
    #pragma unroll
    for (int m = 0; m < 4; ++m) {
        v2f r;
        r.x = acc0[m] * sc.x;
        r.y = acc1[m] * sc.y;
        *(v2f*)&red[kq][m][lane * 2] = r;
    }
    __syncthreads();

    const int o = tid * 2;                    // 512 partials, 2 per thread
    const int m = o >> 7;
    const int c = o & 127;
    const float* rb = &red[0][m][c];
    v2f p = *(const v2f*)rb;
    #pragma unroll
    for (int k = 1; k < 4; ++k) {
        const v2f q = *(const v2f*)(rb + k * 4 * TILE_N);
        p.x += q.x;
        p.y += q.y;
    }
    *(v2f*)(ws + (size_t)(g * 4 + m) * OUT_F + bx * TILE_N + c) = p;
}

// ============ Stage 2: reduce NGROUPS partials + bias ============
__global__ __launch_bounds__(256) void gptq_s2(
    const float* __restrict__ ws,      // [NGROUPS, 4, OUT_F]
    const float* __restrict__ bias,
    float*       __restrict__ out)     // [4, OUT_F]
{
    const int n = blockIdx.x * 256 + threadIdx.x;   // 11008 = 43*256
    const int m = blockIdx.y;
    float s0 = bias[n], s1 = 0.f, s2 = 0.f, s3 = 0.f;
    #pragma unroll
    for (int g = 0; g < NGROUPS; g += 4) {
        s0 += ws[(size_t)((g + 0) * 4 + m) * OUT_F + n];
        s1 += ws[(size_t)((g + 1) * 4 + m) * OUT_F + n];
        s2 += ws[(size_t)((g + 2) * 4 + m) * OUT_F + n];
        s3 += ws[(size_t)((g + 3) * 4 + m) * OUT_F + n];
    }
    out[m * OUT_F + n] = (s0 + s1) + (s2 + s3);
}

// ============ Fallback: round-2 proven two-stage (ws >= 1.4 MB) ============
__global__ __launch_bounds__(256) void gptq_partial_kernel(
    const float* __restrict__ x, const float* __restrict__ scales,
    const int* __restrict__ qweight, const int* __restrict__ qzeros,
    float* __restrict__ ws)
{
    __shared__ float part[4][4][64];
    const int tid = threadIdx.x;
    const int col = tid & 63;
    const int kp  = tid >> 6;
    const int n   = blockIdx.x * 64 + col;
    const int g   = blockIdx.y * 4 + kp;
    const int gu  = __builtin_amdgcn_readfirstlane(g);
    const unsigned qz = (unsigned)qzeros[g * ZCOLS + (n >> 3)];
    const float zf = (float)(((qz >> (4u * (unsigned)(n & 7))) & 0xFu) + 1u);
    const float sc = scales[g * OUT_F + n];
    float ga[4] = {0.f, 0.f, 0.f, 0.f};
    const int kkbase = gu * (GROUPSIZE / 8);
    #pragma unroll
    for (int t = 0; t < GROUPSIZE / 8; ++t) {
        const int kk = kkbase + t;
        const unsigned w = (unsigned)qweight[kk * OUT_F + n];
        const unsigned lo = w & 0x0F0F0F0Fu;
        const unsigned hi = (w >> 4) & 0x0F0F0F0Fu;
        float q[8];
        q[0] = (float)(lo & 0xFFu);         q[1] = (float)(hi & 0xFFu);
        q[2] = (float)((lo >> 8) & 0xFFu);  q[3] = (float)((hi >> 8) & 0xFFu);
        q[4] = (float)((lo >> 16) & 0xFFu); q[5] = (float)((hi >> 16) & 0xFFu);
        q[6] = (float)(lo >> 24);           q[7] = (float)(hi >> 24);
        const int k0 = kk * 8;
        #pragma unroll
        for (int j = 0; j < 8; ++j) {
            const float d = q[j] - zf;
            #pragma unroll
            for (int m = 0; m < 4; ++m) ga[m] += x[m * IN_F + k0 + j] * d;
        }
    }
    #pragma unroll
    for (int m = 0; m < 4; ++m) part[kp][m][col] = sc * ga[m];
    __syncthreads();
    const int m = tid >> 6;
    const int c = tid & 63;
    const int nn = blockIdx.x * 64 + c;
    const float s = part[0][m][c] + part[1][m][c] + part[2][m][c] + part[3][m][c];
    ws[(blockIdx.y * 4 + m) * OUT_F + nn] = s;
}

__global__ __launch_bounds__(256) void gptq_reduce_kernel(
    const float* __restrict__ ws, const float* __restrict__ bias,
    float* __restrict__ out)
{
    const int n = blockIdx.x * 256 + threadIdx.x;
    const int m = blockIdx.y;
    float s = bias[n];
    #pragma unroll
    for (int ks = 0; ks < 8; ++ks) s += ws[(ks * 4 + m) * OUT_F + n];
    out[m * OUT_F + n] = s;
}

extern "C" void kernel_launch(void* const* d_in, const int* in_sizes, int n_in,
                              void* d_out, int out_size, void* d_ws, size_t ws_size,
                              hipStream_t stream) {
    const float* x       = (const float*)d_in[0];
    const float* scales  = (const float*)d_in[1];
    const float* bias    = (const float*)d_in[2];
    const int*   qweight = (const int*)d_in[3];
    const int*   qzeros  = (const int*)d_in[4];
    float*       out     = (float*)d_out;

    if (ws_size >= WS_NEW_BYTES) {
        float* ws = (float*)d_ws;
        dim3 g1(NTILES, NGROUPS);    // (86, 32) = 2752 blocks
        gptq_s1<<<g1, 256, 0, stream>>>(x, scales, qweight, qzeros, ws);
        dim3 g2(OUT_F / 256, 4);     // (43, 4)
        gptq_s2<<<g2, 256, 0, stream>>>(ws, bias, out);
    } else if (ws_size >= WS_OLD_BYTES) {
        float* ws = (float*)d_ws;
        dim3 g1(OUT_F / 64, 8);
        gptq_partial_kernel<<<g1, 256, 0, stream>>>(x, scales, qweight, qzeros, ws);
        dim3 g2(OUT_F / 256, 4);
        gptq_reduce_kernel<<<g2, 256, 0, stream>>>(ws, bias, out);
    }
}